// Round 2
// baseline (1316.477 us; speedup 1.0000x reference)
//
#include <hip/hip_runtime.h>
#include <hip/hip_bf16.h>

// Sizes (fixed by the reference)
#define B_  1024
#define P_  20
#define L_  3
#define T_  5
#define E_  128
#define N_  (B_*P_)        // 20480 sequences
#define DDOC 768
#define DENT 100

__device__ __forceinline__ float sigmoidf_(float x) { return 1.f / (1.f + expf(-x)); }

// ---------------------------------------------------------------------------
// Kernel 1: news_compress for item1 (rows 0..1023) and item2 (rows 1024..2047)
// out = tanh(elu(d @ W1 + b1) @ W2 + b2),  d: [768], out: [128]
// block = 256 threads, 8 rows/block
// ---------------------------------------------------------------------------
__global__ __launch_bounds__(256) void news_kernel(
    const int* __restrict__ item1, const int* __restrict__ item2,
    const float* __restrict__ doc_table,
    const float* __restrict__ W1, const float* __restrict__ b1,
    const float* __restrict__ W2, const float* __restrict__ b2,
    float* __restrict__ news_c)
{
    __shared__ float d_lds[8][DDOC];
    __shared__ float h1_lds[8][132];
    const int tid = threadIdx.x;
    const int row0 = blockIdx.x * 8;

    // stage 8 doc rows (8*768 floats = 1536 float4)
    for (int i = tid; i < 8 * 192; i += 256) {
        int r = i / 192, q = i % 192;
        int gr = row0 + r;
        int id = (gr < B_) ? item1[gr] : item2[gr - B_];
        reinterpret_cast<float4*>(&d_lds[r][0])[q] =
            reinterpret_cast<const float4*>(doc_table + (size_t)id * DDOC)[q];
    }
    __syncthreads();

    const int tn = tid & 127;   // output col
    const int tm = tid >> 7;    // 0/1 -> rows tm*4..tm*4+3
    float acc[4];
#pragma unroll
    for (int r = 0; r < 4; r++) acc[r] = b1[tn];

    for (int k = 0; k < DDOC; k += 4) {
        float w0 = W1[(k + 0) * 128 + tn];
        float w1 = W1[(k + 1) * 128 + tn];
        float w2 = W1[(k + 2) * 128 + tn];
        float w3 = W1[(k + 3) * 128 + tn];
#pragma unroll
        for (int r = 0; r < 4; r++) {
            const float4 dv = *reinterpret_cast<const float4*>(&d_lds[tm * 4 + r][k]);
            acc[r] = fmaf(dv.x, w0, acc[r]);
            acc[r] = fmaf(dv.y, w1, acc[r]);
            acc[r] = fmaf(dv.z, w2, acc[r]);
            acc[r] = fmaf(dv.w, w3, acc[r]);
        }
    }
#pragma unroll
    for (int r = 0; r < 4; r++) {
        float v = acc[r];
        h1_lds[tm * 4 + r][tn] = (v > 0.f) ? v : expm1f(v);   // ELU(alpha=1)
    }
    __syncthreads();

    float acc2[4];
#pragma unroll
    for (int r = 0; r < 4; r++) acc2[r] = b2[tn];
    for (int k = 0; k < 128; k += 4) {
        float w0 = W2[(k + 0) * 128 + tn];
        float w1 = W2[(k + 1) * 128 + tn];
        float w2 = W2[(k + 2) * 128 + tn];
        float w3 = W2[(k + 3) * 128 + tn];
#pragma unroll
        for (int r = 0; r < 4; r++) {
            const float4 hv = *reinterpret_cast<const float4*>(&h1_lds[tm * 4 + r][k]);
            acc2[r] = fmaf(hv.x, w0, acc2[r]);
            acc2[r] = fmaf(hv.y, w1, acc2[r]);
            acc2[r] = fmaf(hv.z, w2, acc2[r]);
            acc2[r] = fmaf(hv.w, w3, acc2[r]);
        }
    }
#pragma unroll
    for (int r = 0; r < 4; r++)
        news_c[(size_t)(row0 + tm * 4 + r) * 128 + tn] = tanhf(acc2[r]);
}

// ---------------------------------------------------------------------------
// Kernel 2: entity/relation compress: out = tanh(table[idx] @ W + b)
// blocks 0..1919: entity (32 rows each); 1920..3839: relation; 3840: rel0 (1 row)
// block 256 threads; weights (100x128) staged in LDS; thread tile 4 rows x 4 cols
// ---------------------------------------------------------------------------
__global__ __launch_bounds__(256) void compress_kernel(
    const int* __restrict__ paths, const int* __restrict__ edges,
    const float* __restrict__ entity_table, const float* __restrict__ relation_table,
    const float* __restrict__ ec_W, const float* __restrict__ ec_b,
    const float* __restrict__ rc_W, const float* __restrict__ rc_b,
    float* __restrict__ node_emb, float* __restrict__ rel_emb, float* __restrict__ rel0)
{
    __shared__ float w_lds[DENT][128];
    __shared__ float x_lds[32][104];
    __shared__ int idx_lds[32];

    const int tid = threadIdx.x;
    const int bid = blockIdx.x;
    const bool is_ent  = (bid < 1920);
    const bool is_rel0 = (bid == 3840);
    const float* W     = is_ent ? ec_W : rc_W;
    const float* bias  = is_ent ? ec_b : rc_b;
    const float* table = is_ent ? entity_table : relation_table;
    float* outp; int nrows; int row0;
    if (is_ent)       { row0 = bid * 32;          outp = node_emb; nrows = 32; }
    else if (!is_rel0){ row0 = (bid - 1920) * 32; outp = rel_emb;  nrows = 32; }
    else              { row0 = 0;                 outp = rel0;     nrows = 1;  }

    // stage W (12800 floats = 3200 float4)
    for (int i = tid; i < 3200; i += 256)
        reinterpret_cast<float4*>(&w_lds[0][0])[i] = reinterpret_cast<const float4*>(W)[i];
    if (tid < nrows) {
        int gr = row0 + tid;
        idx_lds[tid] = is_rel0 ? 0 : (is_ent ? paths[gr] : edges[gr]);
    }
    __syncthreads();

    // stage gathered rows (nrows * 25 float4)
    for (int i = tid; i < nrows * 25; i += 256) {
        int r = i / 25, q = i % 25;
        reinterpret_cast<float4*>(&x_lds[r][0])[q] =
            reinterpret_cast<const float4*>(table + (size_t)idx_lds[r] * DENT)[q];
    }
    __syncthreads();

    const int tn = tid & 31;   // col group: cols tn*4..+3
    const int tm = tid >> 5;   // row group: rows tm*4..+3
    float acc[4][4];
#pragma unroll
    for (int ri = 0; ri < 4; ri++)
#pragma unroll
        for (int cj = 0; cj < 4; cj++) acc[ri][cj] = bias[tn * 4 + cj];

    for (int k = 0; k < DENT; k += 4) {
        float4 wv[4];
#pragma unroll
        for (int kk = 0; kk < 4; kk++)
            wv[kk] = *reinterpret_cast<const float4*>(&w_lds[k + kk][tn * 4]);
#pragma unroll
        for (int ri = 0; ri < 4; ri++) {
            const float4 xv = *reinterpret_cast<const float4*>(&x_lds[tm * 4 + ri][k]);
            float xs[4] = {xv.x, xv.y, xv.z, xv.w};
#pragma unroll
            for (int kk = 0; kk < 4; kk++) {
                acc[ri][0] = fmaf(xs[kk], wv[kk].x, acc[ri][0]);
                acc[ri][1] = fmaf(xs[kk], wv[kk].y, acc[ri][1]);
                acc[ri][2] = fmaf(xs[kk], wv[kk].z, acc[ri][2]);
                acc[ri][3] = fmaf(xs[kk], wv[kk].w, acc[ri][3]);
            }
        }
    }
#pragma unroll
    for (int ri = 0; ri < 4; ri++) {
        int r = tm * 4 + ri;
        if (r < nrows) {
            float4 o;
            o.x = tanhf(acc[ri][0]); o.y = tanhf(acc[ri][1]);
            o.z = tanhf(acc[ri][2]); o.w = tanhf(acc[ri][3]);
            *reinterpret_cast<float4*>(&outp[(size_t)(row0 + r) * 128 + tn * 4]) = o;
        }
    }
}

// ---------------------------------------------------------------------------
// Kernel 3: one LSTM step (launched 5x, t=0..4)
// gates = b + node@Wn^T + rel@Wr^T + h@Wh^T ; cell update.
// grid = 640 row-blocks x 4 hd-blocks; block 256 thr; tile 32 rows x 32 hd x 4 gates
// K chunked by 16 into LDS. t==0: h,c treated as 0 (skip K=256..383).
// ---------------------------------------------------------------------------
__global__ __launch_bounds__(256) void lstm_step(
    int t,
    const float* __restrict__ news_c, const float* __restrict__ node_emb,
    const float* __restrict__ rel_emb, const float* __restrict__ rel0,
    const float* __restrict__ W_ih, const float* __restrict__ W_hh,
    const float* __restrict__ b_ih, const float* __restrict__ b_hh,
    float* __restrict__ h_buf, float* __restrict__ c_buf)
{
    __shared__ float w_lds[128 * 20];         // 128 local gate-rows, 16 k (pad->20)
    __shared__ float x_lds[32 * 16];          // 32 rows x 16 k
    __shared__ const float* nptr[32];
    __shared__ const float* rptr[32];

    const int tid  = threadIdx.x;
    const int rb   = blockIdx.x >> 2;
    const int hd0  = (blockIdx.x & 3) * 32;
    const int row0 = rb * 32;

    if (tid < 32) {
        int n = row0 + tid;
        int b = n / P_;
        const float* np;
        if (t == 0)      np = news_c + (size_t)b * 128;
        else if (t == 4) np = news_c + (size_t)(B_ + b) * 128;
        else             np = node_emb + (size_t)(n * 3 + (t - 1)) * 128;
        nptr[tid] = np;
        rptr[tid] = (t < 3) ? (rel_emb + (size_t)(n * 3 + t) * 128) : rel0;
    }

    const int tn = tid & 31;   // local hidden dim
    const int tm = tid >> 5;   // row group (8 groups x 4 rows)
    const int hd = hd0 + tn;

    float acc[4][4];           // [row][gate]
#pragma unroll
    for (int ri = 0; ri < 4; ri++)
#pragma unroll
        for (int g = 0; g < 4; g++)
            acc[ri][g] = b_ih[g * 128 + hd] + b_hh[g * 128 + hd];

    const int nchunks = (t == 0) ? 16 : 24;
    __syncthreads();

    for (int ch = 0; ch < nchunks; ch++) {
        const int k0 = ch * 16;
        const float* Wsrc; int Ks, k0s;
        if (k0 < 256) { Wsrc = W_ih; Ks = 256; k0s = k0; }
        else          { Wsrc = W_hh; Ks = 128; k0s = k0 - 256; }

        // stage 128 gate-rows x 16 k  (512 float4)
        for (int i = tid; i < 512; i += 256) {
            int lr = i >> 2, q = i & 3;
            int g = lr >> 5, hdl = lr & 31;
            int grow = g * 128 + hd0 + hdl;
            *reinterpret_cast<float4*>(&w_lds[lr * 20 + q * 4]) =
                *reinterpret_cast<const float4*>(&Wsrc[(size_t)grow * Ks + k0s + q * 4]);
        }
        // stage 32 rows x 16 k (128 float4)
        if (tid < 128) {
            int r = tid >> 2, q = tid & 3;
            const float* src;
            if (k0 < 128)      src = nptr[r] + k0;
            else if (k0 < 256) src = rptr[r] + (k0 - 128);
            else               src = h_buf + (size_t)(row0 + r) * 128 + (k0 - 256);
            *reinterpret_cast<float4*>(&x_lds[r * 16 + q * 4]) =
                *reinterpret_cast<const float4*>(src + q * 4);
        }
        __syncthreads();

#pragma unroll
        for (int k = 0; k < 16; k += 4) {
            float4 wv[4];
#pragma unroll
            for (int g = 0; g < 4; g++)
                wv[g] = *reinterpret_cast<const float4*>(&w_lds[(g * 32 + tn) * 20 + k]);
#pragma unroll
            for (int ri = 0; ri < 4; ri++) {
                const float4 xv = *reinterpret_cast<const float4*>(&x_lds[(tm * 4 + ri) * 16 + k]);
#pragma unroll
                for (int g = 0; g < 4; g++) {
                    acc[ri][g] = fmaf(xv.x, wv[g].x, acc[ri][g]);
                    acc[ri][g] = fmaf(xv.y, wv[g].y, acc[ri][g]);
                    acc[ri][g] = fmaf(xv.z, wv[g].z, acc[ri][g]);
                    acc[ri][g] = fmaf(xv.w, wv[g].w, acc[ri][g]);
                }
            }
        }
        __syncthreads();
    }

    // cell update for 4 rows, this thread's hidden dim
#pragma unroll
    for (int ri = 0; ri < 4; ri++) {
        int n = row0 + tm * 4 + ri;
        size_t off = (size_t)n * 128 + hd;
        float cp = (t == 0) ? 0.f : c_buf[off];
        float gi = sigmoidf_(acc[ri][0]);
        float gf = sigmoidf_(acc[ri][1]);
        float gg = tanhf(acc[ri][2]);
        float go = sigmoidf_(acc[ri][3]);
        float cn = gf * cp + gi * gg;
        c_buf[off] = cn;
        h_buf[off] = go * tanhf(cn);
    }
}

// ---------------------------------------------------------------------------
// Kernel 4: scores = relu(h @ W1 + b1) @ W2 + b2   (16 rows/block)
// ---------------------------------------------------------------------------
__global__ __launch_bounds__(256) void mlp_kernel(
    const float* __restrict__ h_buf,
    const float* __restrict__ W1, const float* __restrict__ b1,
    const float* __restrict__ W2, const float* __restrict__ b2,
    float* __restrict__ scores)   // scores segment of d_out
{
    __shared__ float h_lds[16][132];
    __shared__ float z_lds[16][132];
    const int tid = threadIdx.x;
    const int row0 = blockIdx.x * 16;

    for (int i = tid; i < 512; i += 256) {
        int r = i >> 5, q = i & 31;
        *reinterpret_cast<float4*>(&h_lds[r][q * 4]) =
            *reinterpret_cast<const float4*>(&h_buf[(size_t)(row0 + r) * 128 + q * 4]);
    }
    __syncthreads();

    const int tn = tid & 127;
    const int tm = tid >> 7;   // 0/1 -> rows tm*8..+7
    float acc[8];
#pragma unroll
    for (int r = 0; r < 8; r++) acc[r] = b1[tn];
    for (int k = 0; k < 128; k += 4) {
        float w0 = W1[(k + 0) * 128 + tn];
        float w1 = W1[(k + 1) * 128 + tn];
        float w2 = W1[(k + 2) * 128 + tn];
        float w3 = W1[(k + 3) * 128 + tn];
#pragma unroll
        for (int r = 0; r < 8; r++) {
            const float4 hv = *reinterpret_cast<const float4*>(&h_lds[tm * 8 + r][k]);
            acc[r] = fmaf(hv.x, w0, acc[r]);
            acc[r] = fmaf(hv.y, w1, acc[r]);
            acc[r] = fmaf(hv.z, w2, acc[r]);
            acc[r] = fmaf(hv.w, w3, acc[r]);
        }
    }
#pragma unroll
    for (int r = 0; r < 8; r++)
        z_lds[tm * 8 + r][tn] = fmaxf(acc[r], 0.f);
    __syncthreads();

    // second layer: 128 -> 1
    const int row = tid >> 4;      // 0..15
    const int part = tid & 15;
    float s = 0.f;
#pragma unroll
    for (int i = 0; i < 8; i++) {
        int j = part + i * 16;
        s += z_lds[row][j] * W2[j];
    }
    s += __shfl_xor(s, 8, 16);
    s += __shfl_xor(s, 4, 16);
    s += __shfl_xor(s, 2, 16);
    s += __shfl_xor(s, 1, 16);
    if (part == 0)
        scores[row0 + row] = s + b2[0];
}

// ---------------------------------------------------------------------------
// Kernel 5: predicts = sigmoid(logsumexp(scores/2)), loss = BCE mean
// one block, 1024 threads (one per batch element)
// ---------------------------------------------------------------------------
__global__ __launch_bounds__(1024) void final_kernel(
    const float* __restrict__ label, const float* scores, float* out)
{
    __shared__ float red[1024];
    const int b = threadIdx.x;
    const float* s = scores + (size_t)b * P_;
    float m = -1e30f;
#pragma unroll
    for (int p = 0; p < P_; p++) m = fmaxf(m, s[p] * 0.5f);
    float sum = 0.f;
#pragma unroll
    for (int p = 0; p < P_; p++) sum += expf(s[p] * 0.5f - m);
    float lse = m + logf(sum);
    float pr = 1.f / (1.f + expf(-lse));
    out[1 + b] = pr;                                   // unclipped predicts
    float pc = fminf(fmaxf(pr, 1e-7f), 1.f - 1e-7f);   // clipped for loss
    float lb = label[b];
    red[b] = -(lb * logf(pc) + (1.f - lb) * logf(1.f - pc));
    __syncthreads();
    for (int st = 512; st > 0; st >>= 1) {
        if (b < st) red[b] += red[b + st];
        __syncthreads();
    }
    if (b == 0) out[0] = red[0] * (1.f / 1024.f);
}

// ---------------------------------------------------------------------------
extern "C" void kernel_launch(void* const* d_in, const int* in_sizes, int n_in,
                              void* d_out, int out_size, void* d_ws, size_t ws_size,
                              hipStream_t stream)
{
    const int*   item1     = (const int*)  d_in[0];
    const int*   item2     = (const int*)  d_in[1];
    const int*   paths     = (const int*)  d_in[2];
    const int*   edges     = (const int*)  d_in[3];
    const float* label     = (const float*)d_in[4];
    const float* doc_table = (const float*)d_in[5];
    const float* ent_table = (const float*)d_in[6];
    const float* rel_table = (const float*)d_in[7];
    const float* nc_W1     = (const float*)d_in[8];
    const float* nc_b1     = (const float*)d_in[9];
    const float* nc_W2     = (const float*)d_in[10];
    const float* nc_b2     = (const float*)d_in[11];
    const float* ec_W      = (const float*)d_in[12];
    const float* ec_b      = (const float*)d_in[13];
    const float* rc_W      = (const float*)d_in[14];
    const float* rc_b      = (const float*)d_in[15];
    const float* W_ih      = (const float*)d_in[16];
    const float* W_hh      = (const float*)d_in[17];
    const float* b_ih      = (const float*)d_in[18];
    const float* b_hh      = (const float*)d_in[19];
    const float* mlp_W1    = (const float*)d_in[20];
    const float* mlp_b1    = (const float*)d_in[21];
    const float* mlp_W2    = (const float*)d_in[22];
    const float* mlp_b2    = (const float*)d_in[23];

    float* ws       = (float*)d_ws;
    float* news_c   = ws;                       // 2048*128      = 262144
    float* node_emb = news_c   + 262144;        // 61440*128     = 7864320
    float* rel_emb  = node_emb + 7864320;       // 61440*128     = 7864320
    float* rel0     = rel_emb  + 7864320;       // 128
    float* h_buf    = rel0     + 128;           // 20480*128     = 2621440
    float* c_buf    = h_buf    + 2621440;       // 20480*128     = 2621440
    float* out      = (float*)d_out;            // [1 | 1024 | 20480]
    float* scores   = out + 1 + B_;

    news_kernel<<<256, 256, 0, stream>>>(item1, item2, doc_table,
                                         nc_W1, nc_b1, nc_W2, nc_b2, news_c);
    compress_kernel<<<3841, 256, 0, stream>>>(paths, edges, ent_table, rel_table,
                                              ec_W, ec_b, rc_W, rc_b,
                                              node_emb, rel_emb, rel0);
    for (int t = 0; t < T_; t++)
        lstm_step<<<2560, 256, 0, stream>>>(t, news_c, node_emb, rel_emb, rel0,
                                            W_ih, W_hh, b_ih, b_hh, h_buf, c_buf);
    mlp_kernel<<<1280, 256, 0, stream>>>(h_buf, mlp_W1, mlp_b1, mlp_W2, mlp_b2, scores);
    final_kernel<<<1, 1024, 0, stream>>>(label, scores, out);
}

// Round 3
// 715.414 us; speedup vs baseline: 1.8402x; 1.8402x over previous
//
#include <hip/hip_runtime.h>
#include <hip/hip_bf16.h>

// Sizes (fixed by the reference)
#define B_  1024
#define P_  20
#define L_  3
#define T_  5
#define E_  128
#define N_  (B_*P_)        // 20480 sequences
#define DDOC 768
#define DENT 100
#define XROWS 124929      // [news1(1024) | news2(1024) | node(61440) | rel(61440) | rel0(1)]

typedef unsigned short u16;
typedef unsigned int   u32;
typedef __attribute__((ext_vector_type(8))) __bf16 bf16x8;
typedef __attribute__((ext_vector_type(4))) float  f32x4;

__device__ __forceinline__ float sigmoidf_(float x) { return 1.f / (1.f + expf(-x)); }
__device__ __forceinline__ u16 f2bf_rne(float x) {
    u32 b = __float_as_uint(x);
    b += 0x7fffu + ((b >> 16) & 1u);
    return (u16)(b >> 16);
}
__device__ __forceinline__ float bf2f(u16 u) { return __uint_as_float(((u32)u) << 16); }
__device__ __forceinline__ u32 pack2(u16 a, u16 b) { return (u32)a | ((u32)b << 16); }

// ---------------------------------------------------------------------------
// Kernel 1: news_compress -> bf16 hi/lo planes rows 0..2047 of X
// ---------------------------------------------------------------------------
__global__ __launch_bounds__(256) void news_kernel(
    const int* __restrict__ item1, const int* __restrict__ item2,
    const float* __restrict__ doc_table,
    const float* __restrict__ W1, const float* __restrict__ b1,
    const float* __restrict__ W2, const float* __restrict__ b2,
    u16* __restrict__ xh, u16* __restrict__ xl)
{
    __shared__ float d_lds[8][DDOC];
    __shared__ float h1_lds[8][132];
    const int tid = threadIdx.x;
    const int row0 = blockIdx.x * 8;

    for (int i = tid; i < 8 * 192; i += 256) {
        int r = i / 192, q = i % 192;
        int gr = row0 + r;
        int id = (gr < B_) ? item1[gr] : item2[gr - B_];
        reinterpret_cast<float4*>(&d_lds[r][0])[q] =
            reinterpret_cast<const float4*>(doc_table + (size_t)id * DDOC)[q];
    }
    __syncthreads();

    const int tn = tid & 127;
    const int tm = tid >> 7;
    float acc[4];
#pragma unroll
    for (int r = 0; r < 4; r++) acc[r] = b1[tn];

    for (int k = 0; k < DDOC; k += 4) {
        float w0 = W1[(k + 0) * 128 + tn];
        float w1 = W1[(k + 1) * 128 + tn];
        float w2 = W1[(k + 2) * 128 + tn];
        float w3 = W1[(k + 3) * 128 + tn];
#pragma unroll
        for (int r = 0; r < 4; r++) {
            const float4 dv = *reinterpret_cast<const float4*>(&d_lds[tm * 4 + r][k]);
            acc[r] = fmaf(dv.x, w0, acc[r]);
            acc[r] = fmaf(dv.y, w1, acc[r]);
            acc[r] = fmaf(dv.z, w2, acc[r]);
            acc[r] = fmaf(dv.w, w3, acc[r]);
        }
    }
#pragma unroll
    for (int r = 0; r < 4; r++) {
        float v = acc[r];
        h1_lds[tm * 4 + r][tn] = (v > 0.f) ? v : expm1f(v);   // ELU
    }
    __syncthreads();

    float acc2[4];
#pragma unroll
    for (int r = 0; r < 4; r++) acc2[r] = b2[tn];
    for (int k = 0; k < 128; k += 4) {
        float w0 = W2[(k + 0) * 128 + tn];
        float w1 = W2[(k + 1) * 128 + tn];
        float w2 = W2[(k + 2) * 128 + tn];
        float w3 = W2[(k + 3) * 128 + tn];
#pragma unroll
        for (int r = 0; r < 4; r++) {
            const float4 hv = *reinterpret_cast<const float4*>(&h1_lds[tm * 4 + r][k]);
            acc2[r] = fmaf(hv.x, w0, acc2[r]);
            acc2[r] = fmaf(hv.y, w1, acc2[r]);
            acc2[r] = fmaf(hv.z, w2, acc2[r]);
            acc2[r] = fmaf(hv.w, w3, acc2[r]);
        }
    }
#pragma unroll
    for (int r = 0; r < 4; r++) {
        float v = tanhf(acc2[r]);
        size_t off = (size_t)(row0 + tm * 4 + r) * 128 + tn;
        u16 hh = f2bf_rne(v);
        xh[off] = hh;
        xl[off] = f2bf_rne(v - bf2f(hh));
    }
}

// ---------------------------------------------------------------------------
// Kernel 2: entity/relation compress -> bf16 hi/lo planes
// node rows -> X rows 2048+gr ; rel rows -> 63488+gr ; rel0 -> 124928
// ---------------------------------------------------------------------------
__global__ __launch_bounds__(256) void compress_kernel(
    const int* __restrict__ paths, const int* __restrict__ edges,
    const float* __restrict__ entity_table, const float* __restrict__ relation_table,
    const float* __restrict__ ec_W, const float* __restrict__ ec_b,
    const float* __restrict__ rc_W, const float* __restrict__ rc_b,
    u16* __restrict__ xh, u16* __restrict__ xl)
{
    __shared__ float w_lds[DENT][128];
    __shared__ float x_lds[32][104];
    __shared__ int idx_lds[32];

    const int tid = threadIdx.x;
    const int bid = blockIdx.x;
    const bool is_ent  = (bid < 1920);
    const bool is_rel0 = (bid == 3840);
    const float* W     = is_ent ? ec_W : rc_W;
    const float* bias  = is_ent ? ec_b : rc_b;
    const float* table = is_ent ? entity_table : relation_table;
    int nrows; int row0; int xbase;
    if (is_ent)        { row0 = bid * 32;          nrows = 32; xbase = 2048; }
    else if (!is_rel0) { row0 = (bid - 1920) * 32; nrows = 32; xbase = 63488; }
    else               { row0 = 0;                 nrows = 1;  xbase = 124928; }

    for (int i = tid; i < 3200; i += 256)
        reinterpret_cast<float4*>(&w_lds[0][0])[i] = reinterpret_cast<const float4*>(W)[i];
    if (tid < nrows) {
        int gr = row0 + tid;
        idx_lds[tid] = is_rel0 ? 0 : (is_ent ? paths[gr] : edges[gr]);
    }
    __syncthreads();

    for (int i = tid; i < nrows * 25; i += 256) {
        int r = i / 25, q = i % 25;
        reinterpret_cast<float4*>(&x_lds[r][0])[q] =
            reinterpret_cast<const float4*>(table + (size_t)idx_lds[r] * DENT)[q];
    }
    __syncthreads();

    const int tn = tid & 31;
    const int tm = tid >> 5;
    float acc[4][4];
#pragma unroll
    for (int ri = 0; ri < 4; ri++)
#pragma unroll
        for (int cj = 0; cj < 4; cj++) acc[ri][cj] = bias[tn * 4 + cj];

    for (int k = 0; k < DENT; k += 4) {
        float4 wv[4];
#pragma unroll
        for (int kk = 0; kk < 4; kk++)
            wv[kk] = *reinterpret_cast<const float4*>(&w_lds[k + kk][tn * 4]);
#pragma unroll
        for (int ri = 0; ri < 4; ri++) {
            const float4 xv = *reinterpret_cast<const float4*>(&x_lds[tm * 4 + ri][k]);
            float xs[4] = {xv.x, xv.y, xv.z, xv.w};
#pragma unroll
            for (int kk = 0; kk < 4; kk++) {
                acc[ri][0] = fmaf(xs[kk], wv[kk].x, acc[ri][0]);
                acc[ri][1] = fmaf(xs[kk], wv[kk].y, acc[ri][1]);
                acc[ri][2] = fmaf(xs[kk], wv[kk].z, acc[ri][2]);
                acc[ri][3] = fmaf(xs[kk], wv[kk].w, acc[ri][3]);
            }
        }
    }
#pragma unroll
    for (int ri = 0; ri < 4; ri++) {
        int r = tm * 4 + ri;
        if (r < nrows) {
            size_t xrow = (size_t)(xbase + row0 + r);
            u16 hh[4], ll[4];
#pragma unroll
            for (int cj = 0; cj < 4; cj++) {
                float v = tanhf(acc[ri][cj]);
                hh[cj] = f2bf_rne(v);
                ll[cj] = f2bf_rne(v - bf2f(hh[cj]));
            }
            uint2 oh, ol;
            oh.x = pack2(hh[0], hh[1]); oh.y = pack2(hh[2], hh[3]);
            ol.x = pack2(ll[0], ll[1]); ol.y = pack2(ll[2], ll[3]);
            *reinterpret_cast<uint2*>(&xh[xrow * 128 + tn * 4]) = oh;
            *reinterpret_cast<uint2*>(&xl[xrow * 128 + tn * 4]) = ol;
        }
    }
}

// ---------------------------------------------------------------------------
// Kernel 3: split LSTM weights to bf16 hi/lo (once per launch)
// ---------------------------------------------------------------------------
__global__ __launch_bounds__(256) void split_w_kernel(
    const float* __restrict__ W_ih, const float* __restrict__ W_hh,
    u16* __restrict__ wih_h, u16* __restrict__ wih_l,
    u16* __restrict__ whh_h, u16* __restrict__ whh_l)
{
    int i = blockIdx.x * 256 + threadIdx.x;
    if (i < 512 * 256) {
        float w = W_ih[i];
        u16 h = f2bf_rne(w);
        wih_h[i] = h; wih_l[i] = f2bf_rne(w - bf2f(h));
    } else {
        int j = i - 512 * 256;
        float w = W_hh[j];
        u16 h = f2bf_rne(w);
        whh_h[j] = h; whh_l[j] = f2bf_rne(w - bf2f(h));
    }
}

// ---------------------------------------------------------------------------
// Kernel 4: LSTM step GEMM (MFMA, split-bf16 3-product fp32 emulation)
// gates[20480,512] = X_t[20480,384] @ W^T   (K: 0-127 node, 128-255 rel, 256-383 h)
// grid = 160 row-blocks x 4 col-blocks; 256 thr = 4 waves; block tile 128x128;
// wave tile 64x64; BK=32; LDS rows padded to 40 bf16 (even bank spread).
// t==0: h==0 -> only 8 K-chunks.
// ---------------------------------------------------------------------------
__global__ __launch_bounds__(256) void lstm_gemm(
    int t,
    const u16* __restrict__ xh, const u16* __restrict__ xl,
    const u16* __restrict__ wih_h, const u16* __restrict__ wih_l,
    const u16* __restrict__ whh_h, const u16* __restrict__ whh_l,
    const u16* __restrict__ h_hi, const u16* __restrict__ h_lo,
    float* __restrict__ gbuf)
{
    __shared__ u16 a_h[128 * 40], a_l[128 * 40], b_h[128 * 40], b_l[128 * 40];
    __shared__ int nrow[128], rrow[128];

    const int tid  = threadIdx.x;
    const int rb   = blockIdx.x >> 2;
    const int cb   = blockIdx.x & 3;
    const int row0 = rb * 128;
    const int gate0 = cb * 128;

    if (tid < 128) {
        int n = row0 + tid;
        int nr;
        if (t == 0)      nr = n / P_;
        else if (t == 4) nr = 1024 + n / P_;
        else             nr = 2048 + n * 3 + (t - 1);
        nrow[tid] = nr;
        rrow[tid] = (t < 3) ? (63488 + n * 3 + t) : 124928;
    }

    f32x4 acc[4][4];
#pragma unroll
    for (int rg = 0; rg < 4; rg++)
#pragma unroll
        for (int cg = 0; cg < 4; cg++)
            acc[rg][cg] = (f32x4){0.f, 0.f, 0.f, 0.f};

    const int ln   = tid & 63;
    const int wv   = tid >> 6;
    const int wrow = (wv >> 1) * 64;
    const int wcol = (wv & 1) * 64;
    const int l15  = ln & 15;
    const int lk   = (ln >> 4) * 8;

    const int nch = (t == 0) ? 8 : 12;
    __syncthreads();

    for (int ch = 0; ch < nch; ch++) {
        const int k0 = ch * 32;
        // stage A (128 rows x 32k, hi+lo) and B (128 gate-rows x 32k, hi+lo): 2048 x 16B
        for (int i = tid; i < 2048; i += 256) {
            const int ab = i >> 10;          // 0 = A, 1 = B (wave-uniform)
            const int pl = (i >> 9) & 1;     // 0 = hi, 1 = lo (wave-uniform)
            const int r  = (i >> 2) & 127;
            const int q  = i & 3;
            const u16* src;
            if (ab == 0) {
                if (k0 < 128)
                    src = (pl ? xl : xh) + (size_t)nrow[r] * 128 + k0 + q * 8;
                else if (k0 < 256)
                    src = (pl ? xl : xh) + (size_t)rrow[r] * 128 + (k0 - 128) + q * 8;
                else
                    src = (pl ? h_lo : h_hi) + (size_t)(row0 + r) * 128 + (k0 - 256) + q * 8;
            } else {
                if (k0 < 256)
                    src = (pl ? wih_l : wih_h) + (size_t)(gate0 + r) * 256 + k0 + q * 8;
                else
                    src = (pl ? whh_l : whh_h) + (size_t)(gate0 + r) * 128 + (k0 - 256) + q * 8;
            }
            u16* dst = (ab ? (pl ? b_l : b_h) : (pl ? a_l : a_h)) + r * 40 + q * 8;
            *reinterpret_cast<uint4*>(dst) = *reinterpret_cast<const uint4*>(src);
        }
        __syncthreads();

        bf16x8 ah[4], al[4], bh[4], bl[4];
#pragma unroll
        for (int g = 0; g < 4; g++) {
            const int ao = (wrow + g * 16 + l15) * 40 + lk;
            ah[g] = *reinterpret_cast<const bf16x8*>(&a_h[ao]);
            al[g] = *reinterpret_cast<const bf16x8*>(&a_l[ao]);
            const int bo = (wcol + g * 16 + l15) * 40 + lk;
            bh[g] = *reinterpret_cast<const bf16x8*>(&b_h[bo]);
            bl[g] = *reinterpret_cast<const bf16x8*>(&b_l[bo]);
        }
#pragma unroll
        for (int rg = 0; rg < 4; rg++)
#pragma unroll
            for (int cg = 0; cg < 4; cg++) {
                acc[rg][cg] = __builtin_amdgcn_mfma_f32_16x16x32_bf16(ah[rg], bh[cg], acc[rg][cg], 0, 0, 0);
                acc[rg][cg] = __builtin_amdgcn_mfma_f32_16x16x32_bf16(al[rg], bh[cg], acc[rg][cg], 0, 0, 0);
                acc[rg][cg] = __builtin_amdgcn_mfma_f32_16x16x32_bf16(ah[rg], bl[cg], acc[rg][cg], 0, 0, 0);
            }
        __syncthreads();
    }

    // epilogue: D frag layout col=lane&15, row=(lane>>4)*4+e  [m89]
#pragma unroll
    for (int rg = 0; rg < 4; rg++)
#pragma unroll
        for (int cg = 0; cg < 4; cg++) {
            const int col = gate0 + wcol + cg * 16 + l15;
#pragma unroll
            for (int e = 0; e < 4; e++) {
                const int row = row0 + wrow + rg * 16 + (ln >> 4) * 4 + e;
                gbuf[(size_t)row * 512 + col] = acc[rg][cg][e];
            }
        }
}

// ---------------------------------------------------------------------------
// Kernel 5: pointwise LSTM cell update; writes h as bf16 hi/lo planes
// ---------------------------------------------------------------------------
__global__ __launch_bounds__(256) void cell_kernel(
    int t,
    const float* __restrict__ gbuf,
    const float* __restrict__ b_ih, const float* __restrict__ b_hh,
    float* __restrict__ cbuf,
    u16* __restrict__ h_hi, u16* __restrict__ h_lo)
{
    const int idx = blockIdx.x * 256 + threadIdx.x;   // 0 .. 20480*128
    const int n  = idx >> 7;
    const int hd = idx & 127;
    const size_t base = (size_t)n * 512 + hd;
    float gi = gbuf[base +   0] + b_ih[hd +   0] + b_hh[hd +   0];
    float gf = gbuf[base + 128] + b_ih[hd + 128] + b_hh[hd + 128];
    float gg = gbuf[base + 256] + b_ih[hd + 256] + b_hh[hd + 256];
    float go = gbuf[base + 384] + b_ih[hd + 384] + b_hh[hd + 384];
    float cp = (t == 0) ? 0.f : cbuf[idx];
    float cn = sigmoidf_(gf) * cp + sigmoidf_(gi) * tanhf(gg);
    cbuf[idx] = cn;
    float hn = sigmoidf_(go) * tanhf(cn);
    u16 hh = f2bf_rne(hn);
    h_hi[idx] = hh;
    h_lo[idx] = f2bf_rne(hn - bf2f(hh));
}

// ---------------------------------------------------------------------------
// Kernel 6: scores = relu(h @ W1 + b1) @ W2 + b2  (h reconstructed hi+lo)
// ---------------------------------------------------------------------------
__global__ __launch_bounds__(256) void mlp_kernel(
    const u16* __restrict__ h_hi, const u16* __restrict__ h_lo,
    const float* __restrict__ W1, const float* __restrict__ b1,
    const float* __restrict__ W2, const float* __restrict__ b2,
    float* __restrict__ scores)
{
    __shared__ float h_lds[16][132];
    __shared__ float z_lds[16][132];
    const int tid = threadIdx.x;
    const int row0 = blockIdx.x * 16;

    {   // one 8-element group per thread: 16 rows x 16 groups
        const int r = tid >> 4, q = tid & 15;
        const size_t off = (size_t)(row0 + r) * 128 + q * 8;
        uint4 vh = *reinterpret_cast<const uint4*>(&h_hi[off]);
        uint4 vl = *reinterpret_cast<const uint4*>(&h_lo[off]);
        const u16* sh = reinterpret_cast<const u16*>(&vh);
        const u16* sl = reinterpret_cast<const u16*>(&vl);
#pragma unroll
        for (int e = 0; e < 8; e++)
            h_lds[r][q * 8 + e] = bf2f(sh[e]) + bf2f(sl[e]);
    }
    __syncthreads();

    const int tn = tid & 127;
    const int tm = tid >> 7;
    float acc[8];
#pragma unroll
    for (int r = 0; r < 8; r++) acc[r] = b1[tn];
    for (int k = 0; k < 128; k += 4) {
        float w0 = W1[(k + 0) * 128 + tn];
        float w1 = W1[(k + 1) * 128 + tn];
        float w2 = W1[(k + 2) * 128 + tn];
        float w3 = W1[(k + 3) * 128 + tn];
#pragma unroll
        for (int r = 0; r < 8; r++) {
            const float4 hv = *reinterpret_cast<const float4*>(&h_lds[tm * 8 + r][k]);
            acc[r] = fmaf(hv.x, w0, acc[r]);
            acc[r] = fmaf(hv.y, w1, acc[r]);
            acc[r] = fmaf(hv.z, w2, acc[r]);
            acc[r] = fmaf(hv.w, w3, acc[r]);
        }
    }
#pragma unroll
    for (int r = 0; r < 8; r++)
        z_lds[tm * 8 + r][tn] = fmaxf(acc[r], 0.f);
    __syncthreads();

    const int row = tid >> 4;
    const int part = tid & 15;
    float s = 0.f;
#pragma unroll
    for (int i = 0; i < 8; i++) {
        int j = part + i * 16;
        s += z_lds[row][j] * W2[j];
    }
    s += __shfl_xor(s, 8, 16);
    s += __shfl_xor(s, 4, 16);
    s += __shfl_xor(s, 2, 16);
    s += __shfl_xor(s, 1, 16);
    if (part == 0)
        scores[row0 + row] = s + b2[0];
}

// ---------------------------------------------------------------------------
// Kernel 7: predicts + loss
// ---------------------------------------------------------------------------
__global__ __launch_bounds__(1024) void final_kernel(
    const float* __restrict__ label, const float* scores, float* out)
{
    __shared__ float red[1024];
    const int b = threadIdx.x;
    const float* s = scores + (size_t)b * P_;
    float m = -1e30f;
#pragma unroll
    for (int p = 0; p < P_; p++) m = fmaxf(m, s[p] * 0.5f);
    float sum = 0.f;
#pragma unroll
    for (int p = 0; p < P_; p++) sum += expf(s[p] * 0.5f - m);
    float lse = m + logf(sum);
    float pr = 1.f / (1.f + expf(-lse));
    out[1 + b] = pr;
    float pc = fminf(fmaxf(pr, 1e-7f), 1.f - 1e-7f);
    float lb = label[b];
    red[b] = -(lb * logf(pc) + (1.f - lb) * logf(1.f - pc));
    __syncthreads();
    for (int st = 512; st > 0; st >>= 1) {
        if (b < st) red[b] += red[b + st];
        __syncthreads();
    }
    if (b == 0) out[0] = red[0] * (1.f / 1024.f);
}

// ---------------------------------------------------------------------------
extern "C" void kernel_launch(void* const* d_in, const int* in_sizes, int n_in,
                              void* d_out, int out_size, void* d_ws, size_t ws_size,
                              hipStream_t stream)
{
    const int*   item1     = (const int*)  d_in[0];
    const int*   item2     = (const int*)  d_in[1];
    const int*   paths     = (const int*)  d_in[2];
    const int*   edges     = (const int*)  d_in[3];
    const float* label     = (const float*)d_in[4];
    const float* doc_table = (const float*)d_in[5];
    const float* ent_table = (const float*)d_in[6];
    const float* rel_table = (const float*)d_in[7];
    const float* nc_W1     = (const float*)d_in[8];
    const float* nc_b1     = (const float*)d_in[9];
    const float* nc_W2     = (const float*)d_in[10];
    const float* nc_b2     = (const float*)d_in[11];
    const float* ec_W      = (const float*)d_in[12];
    const float* ec_b      = (const float*)d_in[13];
    const float* rc_W      = (const float*)d_in[14];
    const float* rc_b      = (const float*)d_in[15];
    const float* W_ih      = (const float*)d_in[16];
    const float* W_hh      = (const float*)d_in[17];
    const float* b_ih      = (const float*)d_in[18];
    const float* b_hh      = (const float*)d_in[19];
    const float* mlp_W1    = (const float*)d_in[20];
    const float* mlp_b1    = (const float*)d_in[21];
    const float* mlp_W2    = (const float*)d_in[22];
    const float* mlp_b2    = (const float*)d_in[23];

    // workspace layout (bytes); total ~127.7 MB
    char* p = (char*)d_ws;
    u16* xh    = (u16*)p;  p += (size_t)XROWS * 128 * 2;
    u16* xl    = (u16*)p;  p += (size_t)XROWS * 128 * 2;
    u16* wih_h = (u16*)p;  p += 512 * 256 * 2;
    u16* wih_l = (u16*)p;  p += 512 * 256 * 2;
    u16* whh_h = (u16*)p;  p += 512 * 128 * 2;
    u16* whh_l = (u16*)p;  p += 512 * 128 * 2;
    float* gbuf = (float*)p; p += (size_t)N_ * 512 * 4;
    float* cbuf = (float*)p; p += (size_t)N_ * 128 * 4;
    u16* h_hi  = (u16*)p;  p += (size_t)N_ * 128 * 2;
    u16* h_lo  = (u16*)p;  p += (size_t)N_ * 128 * 2;

    float* out    = (float*)d_out;           // [loss | predicts(1024) | scores(20480)]
    float* scores = out + 1 + B_;

    news_kernel<<<256, 256, 0, stream>>>(item1, item2, doc_table,
                                         nc_W1, nc_b1, nc_W2, nc_b2, xh, xl);
    compress_kernel<<<3841, 256, 0, stream>>>(paths, edges, ent_table, rel_table,
                                              ec_W, ec_b, rc_W, rc_b, xh, xl);
    split_w_kernel<<<768, 256, 0, stream>>>(W_ih, W_hh, wih_h, wih_l, whh_h, whh_l);

    for (int t = 0; t < T_; t++) {
        lstm_gemm<<<640, 256, 0, stream>>>(t, xh, xl, wih_h, wih_l, whh_h, whh_l,
                                           h_hi, h_lo, gbuf);
        cell_kernel<<<N_ * 128 / 256, 256, 0, stream>>>(t, gbuf, b_ih, b_hh,
                                                        cbuf, h_hi, h_lo);
    }
    mlp_kernel<<<1280, 256, 0, stream>>>(h_hi, h_lo, mlp_W1, mlp_b1, mlp_W2, mlp_b2, scores);
    final_kernel<<<1, 1024, 0, stream>>>(label, scores, out);
}

// Round 4
// 583.656 us; speedup vs baseline: 2.2556x; 1.2257x over previous
//
#include <hip/hip_runtime.h>
#include <hip/hip_bf16.h>

// Sizes (fixed by the reference)
#define B_  1024
#define P_  20
#define L_  3
#define T_  5
#define E_  128
#define N_  (B_*P_)        // 20480 sequences
#define DDOC 768
#define DENT 100
// X row map: [news1 1024 | news2 1024 | node 61440 | rel_c 60] = 63548 rows
#define NODE_BASE 2048
#define RELC_BASE 63488
#define XROWS 63548

typedef unsigned short u16;
typedef unsigned int   u32;
typedef __attribute__((ext_vector_type(8))) __bf16 bf16x8;
typedef __attribute__((ext_vector_type(4))) float  f32x4;

__device__ __forceinline__ float sigmoidf_(float x) { return 1.f / (1.f + expf(-x)); }
__device__ __forceinline__ u16 f2bf_rne(float x) {
    u32 b = __float_as_uint(x);
    b += 0x7fffu + ((b >> 16) & 1u);
    return (u16)(b >> 16);
}
__device__ __forceinline__ float bf2f(u16 u) { return __uint_as_float(((u32)u) << 16); }
__device__ __forceinline__ u32 pack2(u16 a, u16 b) { return (u32)a | ((u32)b << 16); }

__device__ __forceinline__ void gl2lds16(const void* g, void* l) {
    __builtin_amdgcn_global_load_lds(
        (const __attribute__((address_space(1))) void*)g,
        (__attribute__((address_space(3))) void*)l, 16, 0, 0);
}

// ---------------------------------------------------------------------------
// Kernel 1: news_compress -> bf16 hi/lo planes, X rows 0..2047
// ---------------------------------------------------------------------------
__global__ __launch_bounds__(256) void news_kernel(
    const int* __restrict__ item1, const int* __restrict__ item2,
    const float* __restrict__ doc_table,
    const float* __restrict__ W1, const float* __restrict__ b1,
    const float* __restrict__ W2, const float* __restrict__ b2,
    u16* __restrict__ xh, u16* __restrict__ xl)
{
    __shared__ float d_lds[8][DDOC];
    __shared__ float h1_lds[8][132];
    const int tid = threadIdx.x;
    const int row0 = blockIdx.x * 8;

    for (int i = tid; i < 8 * 192; i += 256) {
        int r = i / 192, q = i % 192;
        int gr = row0 + r;
        int id = (gr < B_) ? item1[gr] : item2[gr - B_];
        reinterpret_cast<float4*>(&d_lds[r][0])[q] =
            reinterpret_cast<const float4*>(doc_table + (size_t)id * DDOC)[q];
    }
    __syncthreads();

    const int tn = tid & 127;
    const int tm = tid >> 7;
    float acc[4];
#pragma unroll
    for (int r = 0; r < 4; r++) acc[r] = b1[tn];

    for (int k = 0; k < DDOC; k += 4) {
        float w0 = W1[(k + 0) * 128 + tn];
        float w1 = W1[(k + 1) * 128 + tn];
        float w2 = W1[(k + 2) * 128 + tn];
        float w3 = W1[(k + 3) * 128 + tn];
#pragma unroll
        for (int r = 0; r < 4; r++) {
            const float4 dv = *reinterpret_cast<const float4*>(&d_lds[tm * 4 + r][k]);
            acc[r] = fmaf(dv.x, w0, acc[r]);
            acc[r] = fmaf(dv.y, w1, acc[r]);
            acc[r] = fmaf(dv.z, w2, acc[r]);
            acc[r] = fmaf(dv.w, w3, acc[r]);
        }
    }
#pragma unroll
    for (int r = 0; r < 4; r++) {
        float v = acc[r];
        h1_lds[tm * 4 + r][tn] = (v > 0.f) ? v : expm1f(v);   // ELU
    }
    __syncthreads();

    float acc2[4];
#pragma unroll
    for (int r = 0; r < 4; r++) acc2[r] = b2[tn];
    for (int k = 0; k < 128; k += 4) {
        float w0 = W2[(k + 0) * 128 + tn];
        float w1 = W2[(k + 1) * 128 + tn];
        float w2 = W2[(k + 2) * 128 + tn];
        float w3 = W2[(k + 3) * 128 + tn];
#pragma unroll
        for (int r = 0; r < 4; r++) {
            const float4 hv = *reinterpret_cast<const float4*>(&h1_lds[tm * 4 + r][k]);
            acc2[r] = fmaf(hv.x, w0, acc2[r]);
            acc2[r] = fmaf(hv.y, w1, acc2[r]);
            acc2[r] = fmaf(hv.z, w2, acc2[r]);
            acc2[r] = fmaf(hv.w, w3, acc2[r]);
        }
    }
#pragma unroll
    for (int r = 0; r < 4; r++) {
        float v = tanhf(acc2[r]);
        size_t off = (size_t)(row0 + tm * 4 + r) * 128 + tn;
        u16 hh = f2bf_rne(v);
        xh[off] = hh;
        xl[off] = f2bf_rne(v - bf2f(hh));
    }
}

// ---------------------------------------------------------------------------
// Kernel 2: prep — split W_ih/W_hh to bf16 hi/lo; build transposed K-padded
// ec/rc weight planes (ecwt[col][k], k<100 valid else 0)
// ---------------------------------------------------------------------------
__global__ __launch_bounds__(256) void prep_kernel(
    const float* __restrict__ W_ih, const float* __restrict__ W_hh,
    const float* __restrict__ ec_W, const float* __restrict__ rc_W,
    u16* __restrict__ wih_h, u16* __restrict__ wih_l,
    u16* __restrict__ whh_h, u16* __restrict__ whh_l,
    u16* __restrict__ ecwt_h, u16* __restrict__ ecwt_l,
    u16* __restrict__ rcwt_h, u16* __restrict__ rcwt_l)
{
    int i = blockIdx.x * 256 + threadIdx.x;
    if (i < 131072) {
        float w = W_ih[i];
        u16 h = f2bf_rne(w);
        wih_h[i] = h; wih_l[i] = f2bf_rne(w - bf2f(h));
    } else if (i < 196608) {
        int j = i - 131072;
        float w = W_hh[j];
        u16 h = f2bf_rne(w);
        whh_h[j] = h; whh_l[j] = f2bf_rne(w - bf2f(h));
    } else if (i < 212992) {
        int j = i - 196608;
        int col = j & 127, k = j >> 7;
        float w = (k < DENT) ? ec_W[k * 128 + col] : 0.f;
        u16 h = f2bf_rne(w);
        ecwt_h[col * 128 + k] = h; ecwt_l[col * 128 + k] = f2bf_rne(w - bf2f(h));
    } else {
        int j = i - 212992;
        int col = j & 127, k = j >> 7;
        float w = (k < DENT) ? rc_W[k * 128 + col] : 0.f;
        u16 h = f2bf_rne(w);
        rcwt_h[col * 128 + k] = h; rcwt_l[col * 128 + k] = f2bf_rne(w - bf2f(h));
    }
}

// ---------------------------------------------------------------------------
// Kernel 3: compress via MFMA: out = tanh(table[idx] @ W + b) -> X hi/lo
// blocks 0..479: entity (128 rows each); block 480: rel_c (60 rows, idx 0..59)
// A staged fp32->hi/lo into LDS rows of 144 B (pad => conflict-floor reads);
// B staged from pre-split transposed planes. Epilogue transposes via LDS
// for coalesced 16 B stores.
// ---------------------------------------------------------------------------
__global__ __launch_bounds__(256) void compress_mfma(
    const int* __restrict__ paths,
    const float* __restrict__ entity_table, const float* __restrict__ relation_table,
    const u16* __restrict__ ecwt_h, const u16* __restrict__ ecwt_l,
    const u16* __restrict__ rcwt_h, const u16* __restrict__ rcwt_l,
    const float* __restrict__ ec_b, const float* __restrict__ rc_b,
    u16* __restrict__ xh, u16* __restrict__ xl)
{
    __shared__ char lds_raw[65536];
    u16* a_lds = (u16*)lds_raw;              // 128 rows x 72 u16 (144 B)
    u16* b_lds = (u16*)(lds_raw + 18432);    // 128 rows x 72 u16
    u32* o_lds = (u32*)lds_raw;              // epilogue: 128 x 128 u32 (64 KB)

    const int tid = threadIdx.x;
    const int bid = blockIdx.x;
    const bool is_rel = (bid == 480);
    const int r0 = bid * 128;
    const u16* wth = is_rel ? rcwt_h : ecwt_h;
    const u16* wtl = is_rel ? rcwt_l : ecwt_l;
    const float* bias = is_rel ? rc_b : ec_b;
    const float* table = is_rel ? relation_table : entity_table;

    const int ar = tid >> 1, ahalf = tid & 1;
    int gidx;
    if (is_rel) gidx = (ar < 60) ? ar : 0;
    else        gidx = paths[r0 + ar];
    const float* arow = table + (size_t)gidx * DENT;

    const int ln = tid & 63, wv = tid >> 6;
    const int wrow = (wv >> 1) * 64, wcol = (wv & 1) * 64;
    const int l15 = ln & 15, lq = ln >> 4;

    f32x4 acc[4][4];
#pragma unroll
    for (int cg = 0; cg < 4; cg++) {
        float bv = bias[wcol + cg * 16 + l15];
#pragma unroll
        for (int rg = 0; rg < 4; rg++)
            acc[rg][cg] = (f32x4){bv, bv, bv, bv};
    }

    for (int c = 0; c < 4; ++c) {
        // stage A: 16 fp32 per thread -> hi/lo bf16
        {
            float v[16];
#pragma unroll
            for (int q = 0; q < 4; ++q) {
                int kq = c * 32 + ahalf * 16 + q * 4;
                float4 f = (kq < DENT) ? *reinterpret_cast<const float4*>(arow + kq)
                                       : make_float4(0.f, 0.f, 0.f, 0.f);
                v[q * 4 + 0] = f.x; v[q * 4 + 1] = f.y;
                v[q * 4 + 2] = f.z; v[q * 4 + 3] = f.w;
            }
            u16 hh[16], llo[16];
#pragma unroll
            for (int e = 0; e < 16; ++e) {
                hh[e] = f2bf_rne(v[e]);
                llo[e] = f2bf_rne(v[e] - bf2f(hh[e]));
            }
            u16* ap = a_lds + ar * 72;
            uint4 o0, o1, o2, o3;
            o0.x = pack2(hh[0], hh[1]);  o0.y = pack2(hh[2], hh[3]);
            o0.z = pack2(hh[4], hh[5]);  o0.w = pack2(hh[6], hh[7]);
            o1.x = pack2(hh[8], hh[9]);  o1.y = pack2(hh[10], hh[11]);
            o1.z = pack2(hh[12], hh[13]); o1.w = pack2(hh[14], hh[15]);
            o2.x = pack2(llo[0], llo[1]);  o2.y = pack2(llo[2], llo[3]);
            o2.z = pack2(llo[4], llo[5]);  o2.w = pack2(llo[6], llo[7]);
            o3.x = pack2(llo[8], llo[9]);  o3.y = pack2(llo[10], llo[11]);
            o3.z = pack2(llo[12], llo[13]); o3.w = pack2(llo[14], llo[15]);
            *reinterpret_cast<uint4*>(ap + ahalf * 16 + 0) = o0;
            *reinterpret_cast<uint4*>(ap + ahalf * 16 + 8) = o1;
            *reinterpret_cast<uint4*>(ap + 32 + ahalf * 16 + 0) = o2;
            *reinterpret_cast<uint4*>(ap + 32 + ahalf * 16 + 8) = o3;
        }
        // stage B: rows = output cols; 32 hi + 32 lo u16 per row
#pragma unroll
        for (int i = 0; i < 4; ++i) {
            int idx = tid + i * 256;
            int br = idx >> 3, s = idx & 7;
            const u16* src = ((s & 4) ? wtl : wth) + br * 128 + c * 32 + (s & 3) * 8;
            *reinterpret_cast<uint4*>(b_lds + br * 72 + s * 8) =
                *reinterpret_cast<const uint4*>(src);
        }
        __syncthreads();

        bf16x8 ah[4], al[4], bh[4], bl[4];
#pragma unroll
        for (int g = 0; g < 4; ++g) {
            const u16* ap = a_lds + (wrow + g * 16 + l15) * 72 + lq * 8;
            ah[g] = *reinterpret_cast<const bf16x8*>(ap);
            al[g] = *reinterpret_cast<const bf16x8*>(ap + 32);
            const u16* bp = b_lds + (wcol + g * 16 + l15) * 72 + lq * 8;
            bh[g] = *reinterpret_cast<const bf16x8*>(bp);
            bl[g] = *reinterpret_cast<const bf16x8*>(bp + 32);
        }
#pragma unroll
        for (int rg = 0; rg < 4; rg++)
#pragma unroll
            for (int cg = 0; cg < 4; cg++) {
                acc[rg][cg] = __builtin_amdgcn_mfma_f32_16x16x32_bf16(ah[rg], bh[cg], acc[rg][cg], 0, 0, 0);
                acc[rg][cg] = __builtin_amdgcn_mfma_f32_16x16x32_bf16(al[rg], bh[cg], acc[rg][cg], 0, 0, 0);
                acc[rg][cg] = __builtin_amdgcn_mfma_f32_16x16x32_bf16(ah[rg], bl[cg], acc[rg][cg], 0, 0, 0);
            }
        __syncthreads();
    }

    // epilogue: tanh + hi/lo pack -> LDS transpose -> coalesced stores
#pragma unroll
    for (int rg = 0; rg < 4; rg++)
#pragma unroll
        for (int cg = 0; cg < 4; cg++) {
            const int col = wcol + cg * 16 + l15;
#pragma unroll
            for (int e = 0; e < 4; ++e) {
                const int row = wrow + rg * 16 + lq * 4 + e;
                float tv = tanhf(acc[rg][cg][e]);
                u16 th = f2bf_rne(tv);
                u16 tl = f2bf_rne(tv - bf2f(th));
                o_lds[row * 128 + col] = pack2(th, tl);
            }
        }
    __syncthreads();
#pragma unroll
    for (int i = 0; i < 8; ++i) {
        int idx = tid + i * 256;         // 0..2047
        int row = idx >> 4, oct = idx & 15;
        int xr;
        if (is_rel) {
            if (row >= 60) continue;
            xr = RELC_BASE + row;
        } else {
            xr = NODE_BASE + r0 + row;
        }
        u32 w[8];
#pragma unroll
        for (int j = 0; j < 8; ++j) w[j] = o_lds[row * 128 + oct * 8 + j];
        uint4 hv, lv;
        hv.x = (w[0] & 0xffffu) | (w[1] << 16);
        hv.y = (w[2] & 0xffffu) | (w[3] << 16);
        hv.z = (w[4] & 0xffffu) | (w[5] << 16);
        hv.w = (w[6] & 0xffffu) | (w[7] << 16);
        lv.x = (w[0] >> 16) | (w[1] & 0xffff0000u);
        lv.y = (w[2] >> 16) | (w[3] & 0xffff0000u);
        lv.z = (w[4] >> 16) | (w[5] & 0xffff0000u);
        lv.w = (w[6] >> 16) | (w[7] & 0xffff0000u);
        *reinterpret_cast<uint4*>(xh + (size_t)xr * 128 + oct * 8) = hv;
        *reinterpret_cast<uint4*>(xl + (size_t)xr * 128 + oct * 8) = lv;
    }
}

// ---------------------------------------------------------------------------
// Kernel 4: LSTM step GEMM (MFMA, split-bf16 3-product)
// gates[20480,512] = X_t[20480,384] @ W^T ; K: 0-127 node, 128-255 rel, 256-383 h
// Staging: global_load_lds w16 with per-lane pre-swizzled sources ->
// linear LDS holds XOR-slot-swizzled tiles (conflict-free ds_read_b128).
// Double-buffered, counted vmcnt(8), raw s_barrier (no drain).
// ---------------------------------------------------------------------------
__global__ __launch_bounds__(256) void lstm_gemm(
    int t,
    const u16* __restrict__ xh, const u16* __restrict__ xl,
    const u16* __restrict__ wih_h, const u16* __restrict__ wih_l,
    const u16* __restrict__ whh_h, const u16* __restrict__ whh_l,
    const u16* __restrict__ h_hi, const u16* __restrict__ h_lo,
    const int* __restrict__ edges,
    float* __restrict__ gbuf)
{
    __shared__ u16 lds_a[2 * 8192];   // 2 x 16 KB, row = 64 u16 (128 B)
    __shared__ u16 lds_b[2 * 8192];

    const int tid  = threadIdx.x;
    const int rb   = blockIdx.x >> 2;
    const int cb   = blockIdx.x & 3;
    const int row0 = rb * 128;
    const int gate0 = cb * 128;

    const int ln = tid & 63, wv = tid >> 6;
    const int wrow = (wv >> 1) * 64, wcol = (wv & 1) * 64;
    const int l15 = ln & 15, lq = ln >> 4;

    // staging lane geometry: op j covers rows 32*wv+8*j .. +7
    const int lr8 = ln >> 3;          // row-within-8
    const int sphys = ln & 7;         // physical 16B slot
    const int slog = sphys ^ lr8;     // logical slot (0-3 hi, 4-7 lo)
    const bool plo = (slog & 4) != 0;
    const int koff = (slog & 3) * 8;  // u16 offset within 32-k chunk

    const u16* nb[4]; const u16* rbp[4]; const u16* hb[4];
    const u16* wb_ih[4]; const u16* wb_hh[4];
#pragma unroll
    for (int j = 0; j < 4; ++j) {
        const int r = 32 * wv + 8 * j + lr8;
        const int n = row0 + r;
        int nr;
        if (t == 0)      nr = n / P_;
        else if (t == 4) nr = 1024 + n / P_;
        else             nr = NODE_BASE + n * 3 + (t - 1);
        nb[j] = (plo ? xl : xh) + (size_t)nr * 128 + koff;
        const int rr = RELC_BASE + ((t < 3) ? edges[n * 3 + t] : 0);
        rbp[j] = (plo ? xl : xh) + (size_t)rr * 128 + koff;
        hb[j] = (plo ? h_lo : h_hi) + (size_t)n * 128 + koff;
        const int gr = gate0 + r;
        wb_ih[j] = (plo ? wih_l : wih_h) + (size_t)gr * 256 + koff;
        wb_hh[j] = (plo ? whh_l : whh_h) + (size_t)gr * 128 + koff;
    }

    f32x4 acc[4][4];
#pragma unroll
    for (int rg = 0; rg < 4; rg++)
#pragma unroll
        for (int cg = 0; cg < 4; cg++)
            acc[rg][cg] = (f32x4){0.f, 0.f, 0.f, 0.f};

    const int nch = (t == 0) ? 8 : 12;

    auto STAGE = [&](int c, int kb) {
        u16* ab = lds_a + kb * 8192;
        u16* bb = lds_b + kb * 8192;
#pragma unroll
        for (int j = 0; j < 4; ++j) {
            const u16* s;
            if (c < 4)      s = nb[j] + c * 32;
            else if (c < 8) s = rbp[j] + (c - 4) * 32;
            else            s = hb[j] + (c - 8) * 32;
            gl2lds16(s, ab + (32 * wv + 8 * j) * 64);
        }
#pragma unroll
        for (int j = 0; j < 4; ++j) {
            const u16* s = (c < 8) ? (wb_ih[j] + c * 32) : (wb_hh[j] + (c - 8) * 32);
            gl2lds16(s, bb + (32 * wv + 8 * j) * 64);
        }
    };

    STAGE(0, 0);
    for (int c = 0; c < nch; ++c) {
        const int kb = c & 1;
        if (c + 1 < nch) {
            STAGE(c + 1, kb ^ 1);
            __builtin_amdgcn_sched_barrier(0);
            asm volatile("s_waitcnt vmcnt(8)" ::: "memory");
        } else {
            asm volatile("s_waitcnt vmcnt(0)" ::: "memory");
        }
        __builtin_amdgcn_s_barrier();
        __builtin_amdgcn_sched_barrier(0);

        const u16* ab = lds_a + kb * 8192;
        const u16* bb = lds_b + kb * 8192;
        bf16x8 ah[4], al[4], bh[4], bl[4];
#pragma unroll
        for (int g = 0; g < 4; ++g) {
            const int r = wrow + g * 16 + l15;
            const u16* ap = ab + r * 64;
            ah[g] = *reinterpret_cast<const bf16x8*>(ap + ((lq    ) ^ (r & 7)) * 8);
            al[g] = *reinterpret_cast<const bf16x8*>(ap + ((lq + 4) ^ (r & 7)) * 8);
            const int rc = wcol + g * 16 + l15;
            const u16* bp = bb + rc * 64;
            bh[g] = *reinterpret_cast<const bf16x8*>(bp + ((lq    ) ^ (rc & 7)) * 8);
            bl[g] = *reinterpret_cast<const bf16x8*>(bp + ((lq + 4) ^ (rc & 7)) * 8);
        }
#pragma unroll
        for (int rg = 0; rg < 4; rg++)
#pragma unroll
            for (int cg = 0; cg < 4; cg++) {
                acc[rg][cg] = __builtin_amdgcn_mfma_f32_16x16x32_bf16(ah[rg], bh[cg], acc[rg][cg], 0, 0, 0);
                acc[rg][cg] = __builtin_amdgcn_mfma_f32_16x16x32_bf16(al[rg], bh[cg], acc[rg][cg], 0, 0, 0);
                acc[rg][cg] = __builtin_amdgcn_mfma_f32_16x16x32_bf16(ah[rg], bl[cg], acc[rg][cg], 0, 0, 0);
            }
        asm volatile("s_waitcnt lgkmcnt(0)" ::: "memory");
        __builtin_amdgcn_s_barrier();
        __builtin_amdgcn_sched_barrier(0);
    }

    // epilogue: D frag layout col=lane&15, row=(lane>>4)*4+e
#pragma unroll
    for (int rg = 0; rg < 4; rg++)
#pragma unroll
        for (int cg = 0; cg < 4; cg++) {
            const int col = gate0 + wcol + cg * 16 + l15;
#pragma unroll
            for (int e = 0; e < 4; e++) {
                const int row = row0 + wrow + rg * 16 + lq * 4 + e;
                gbuf[(size_t)row * 512 + col] = acc[rg][cg][e];
            }
        }
}

// ---------------------------------------------------------------------------
// Kernel 5: pointwise LSTM cell update; writes h as bf16 hi/lo planes
// ---------------------------------------------------------------------------
__global__ __launch_bounds__(256) void cell_kernel(
    int t,
    const float* __restrict__ gbuf,
    const float* __restrict__ b_ih, const float* __restrict__ b_hh,
    float* __restrict__ cbuf,
    u16* __restrict__ h_hi, u16* __restrict__ h_lo)
{
    const int idx = blockIdx.x * 256 + threadIdx.x;
    const int n  = idx >> 7;
    const int hd = idx & 127;
    const size_t base = (size_t)n * 512 + hd;
    float gi = gbuf[base +   0] + b_ih[hd +   0] + b_hh[hd +   0];
    float gf = gbuf[base + 128] + b_ih[hd + 128] + b_hh[hd + 128];
    float gg = gbuf[base + 256] + b_ih[hd + 256] + b_hh[hd + 256];
    float go = gbuf[base + 384] + b_ih[hd + 384] + b_hh[hd + 384];
    float cp = (t == 0) ? 0.f : cbuf[idx];
    float cn = sigmoidf_(gf) * cp + sigmoidf_(gi) * tanhf(gg);
    cbuf[idx] = cn;
    float hn = sigmoidf_(go) * tanhf(cn);
    u16 hh = f2bf_rne(hn);
    h_hi[idx] = hh;
    h_lo[idx] = f2bf_rne(hn - bf2f(hh));
}

// ---------------------------------------------------------------------------
// Kernel 6: scores = relu(h @ W1 + b1) @ W2 + b2
// ---------------------------------------------------------------------------
__global__ __launch_bounds__(256) void mlp_kernel(
    const u16* __restrict__ h_hi, const u16* __restrict__ h_lo,
    const float* __restrict__ W1, const float* __restrict__ b1,
    const float* __restrict__ W2, const float* __restrict__ b2,
    float* __restrict__ scores)
{
    __shared__ float h_lds[16][132];
    __shared__ float z_lds[16][132];
    const int tid = threadIdx.x;
    const int row0 = blockIdx.x * 16;

    {
        const int r = tid >> 4, q = tid & 15;
        const size_t off = (size_t)(row0 + r) * 128 + q * 8;
        uint4 vh = *reinterpret_cast<const uint4*>(&h_hi[off]);
        uint4 vl = *reinterpret_cast<const uint4*>(&h_lo[off]);
        const u16* sh = reinterpret_cast<const u16*>(&vh);
        const u16* sl = reinterpret_cast<const u16*>(&vl);
#pragma unroll
        for (int e = 0; e < 8; e++)
            h_lds[r][q * 8 + e] = bf2f(sh[e]) + bf2f(sl[e]);
    }
    __syncthreads();

    const int tn = tid & 127;
    const int tm = tid >> 7;
    float acc[8];
#pragma unroll
    for (int r = 0; r < 8; r++) acc[r] = b1[tn];
    for (int k = 0; k < 128; k += 4) {
        float w0 = W1[(k + 0) * 128 + tn];
        float w1 = W1[(k + 1) * 128 + tn];
        float w2 = W1[(k + 2) * 128 + tn];
        float w3 = W1[(k + 3) * 128 + tn];
#pragma unroll
        for (int r = 0; r < 8; r++) {
            const float4 hv = *reinterpret_cast<const float4*>(&h_lds[tm * 8 + r][k]);
            acc[r] = fmaf(hv.x, w0, acc[r]);
            acc[r] = fmaf(hv.y, w1, acc[r]);
            acc[r] = fmaf(hv.z, w2, acc[r]);
            acc[r] = fmaf(hv.w, w3, acc[r]);
        }
    }
#pragma unroll
    for (int r = 0; r < 8; r++)
        z_lds[tm * 8 + r][tn] = fmaxf(acc[r], 0.f);
    __syncthreads();

    const int row = tid >> 4;
    const int part = tid & 15;
    float s = 0.f;
#pragma unroll
    for (int i = 0; i < 8; i++) {
        int j = part + i * 16;
        s += z_lds[row][j] * W2[j];
    }
    s += __shfl_xor(s, 8, 16);
    s += __shfl_xor(s, 4, 16);
    s += __shfl_xor(s, 2, 16);
    s += __shfl_xor(s, 1, 16);
    if (part == 0)
        scores[row0 + row] = s + b2[0];
}

// ---------------------------------------------------------------------------
// Kernel 7: predicts + loss
// ---------------------------------------------------------------------------
__global__ __launch_bounds__(1024) void final_kernel(
    const float* __restrict__ label, const float* scores, float* out)
{
    __shared__ float red[1024];
    const int b = threadIdx.x;
    const float* s = scores + (size_t)b * P_;
    float m = -1e30f;
#pragma unroll
    for (int p = 0; p < P_; p++) m = fmaxf(m, s[p] * 0.5f);
    float sum = 0.f;
#pragma unroll
    for (int p = 0; p < P_; p++) sum += expf(s[p] * 0.5f - m);
    float lse = m + logf(sum);
    float pr = 1.f / (1.f + expf(-lse));
    out[1 + b] = pr;
    float pc = fminf(fmaxf(pr, 1e-7f), 1.f - 1e-7f);
    float lb = label[b];
    red[b] = -(lb * logf(pc) + (1.f - lb) * logf(1.f - pc));
    __syncthreads();
    for (int st = 512; st > 0; st >>= 1) {
        if (b < st) red[b] += red[b + st];
        __syncthreads();
    }
    if (b == 0) out[0] = red[0] * (1.f / 1024.f);
}

// ---------------------------------------------------------------------------
extern "C" void kernel_launch(void* const* d_in, const int* in_sizes, int n_in,
                              void* d_out, int out_size, void* d_ws, size_t ws_size,
                              hipStream_t stream)
{
    const int*   item1     = (const int*)  d_in[0];
    const int*   item2     = (const int*)  d_in[1];
    const int*   paths     = (const int*)  d_in[2];
    const int*   edges     = (const int*)  d_in[3];
    const float* label     = (const float*)d_in[4];
    const float* doc_table = (const float*)d_in[5];
    const float* ent_table = (const float*)d_in[6];
    const float* rel_table = (const float*)d_in[7];
    const float* nc_W1     = (const float*)d_in[8];
    const float* nc_b1     = (const float*)d_in[9];
    const float* nc_W2     = (const float*)d_in[10];
    const float* nc_b2     = (const float*)d_in[11];
    const float* ec_W      = (const float*)d_in[12];
    const float* ec_b      = (const float*)d_in[13];
    const float* rc_W      = (const float*)d_in[14];
    const float* rc_b      = (const float*)d_in[15];
    const float* W_ih      = (const float*)d_in[16];
    const float* W_hh      = (const float*)d_in[17];
    const float* b_ih      = (const float*)d_in[18];
    const float* b_hh      = (const float*)d_in[19];
    const float* mlp_W1    = (const float*)d_in[20];
    const float* mlp_b1    = (const float*)d_in[21];
    const float* mlp_W2    = (const float*)d_in[22];
    const float* mlp_b2    = (const float*)d_in[23];

    // workspace layout
    char* p = (char*)d_ws;
    u16* xh     = (u16*)p;  p += (size_t)XROWS * 128 * 2;
    u16* xl     = (u16*)p;  p += (size_t)XROWS * 128 * 2;
    u16* wih_h  = (u16*)p;  p += 131072 * 2;
    u16* wih_l  = (u16*)p;  p += 131072 * 2;
    u16* whh_h  = (u16*)p;  p += 65536 * 2;
    u16* whh_l  = (u16*)p;  p += 65536 * 2;
    u16* ecwt_h = (u16*)p;  p += 16384 * 2;
    u16* ecwt_l = (u16*)p;  p += 16384 * 2;
    u16* rcwt_h = (u16*)p;  p += 16384 * 2;
    u16* rcwt_l = (u16*)p;  p += 16384 * 2;
    float* gbuf = (float*)p; p += (size_t)N_ * 512 * 4;
    float* cbuf = (float*)p; p += (size_t)N_ * 128 * 4;
    u16* h_hi   = (u16*)p;  p += (size_t)N_ * 128 * 2;
    u16* h_lo   = (u16*)p;  p += (size_t)N_ * 128 * 2;

    float* out    = (float*)d_out;           // [loss | predicts(1024) | scores(20480)]
    float* scores = out + 1 + B_;

    news_kernel<<<256, 256, 0, stream>>>(item1, item2, doc_table,
                                         nc_W1, nc_b1, nc_W2, nc_b2, xh, xl);
    prep_kernel<<<896, 256, 0, stream>>>(W_ih, W_hh, ec_W, rc_W,
                                         wih_h, wih_l, whh_h, whh_l,
                                         ecwt_h, ecwt_l, rcwt_h, rcwt_l);
    compress_mfma<<<481, 256, 0, stream>>>(paths, ent_table, rel_table,
                                           ecwt_h, ecwt_l, rcwt_h, rcwt_l,
                                           ec_b, rc_b, xh, xl);
    for (int t = 0; t < T_; t++) {
        lstm_gemm<<<640, 256, 0, stream>>>(t, xh, xl, wih_h, wih_l, whh_h, whh_l,
                                           h_hi, h_lo, edges, gbuf);
        cell_kernel<<<N_ * 128 / 256, 256, 0, stream>>>(t, gbuf, b_ih, b_hh,
                                                        cbuf, h_hi, h_lo);
    }
    mlp_kernel<<<1280, 256, 0, stream>>>(h_hi, h_lo, mlp_W1, mlp_b1, mlp_W2, mlp_b2, scores);
    final_kernel<<<1, 1024, 0, stream>>>(label, scores, out);
}